// Round 3
// baseline (224.368 us; speedup 1.0000x reference)
//
#include <hip/hip_runtime.h>

// Problem constants (from reference setup_inputs)
#define BB  16
#define LL  100
#define LOC 2000
#define EE  16

// SU=500, SL=0, TU=3600, TL=0
// out[b,l,j,e] = base[e] + coef[e] * ds[j]
//
// Round-3 change (single variable): store ADDRESS PATTERN.
// Previous rounds: wave w stored 1KB chunks at a 4KB stride (flat float4
// offset 64w + lane + 256i). Three different instruction schedules (rolled
// loads / reg preload / LDS) all stuck at ~2.1 TB/s writes, so the limiter
// is the HBM-side pattern, not waitcnt scheduling. Now each wave owns a
// CONTIGUOUS 32KB quarter of the block's 128KB output: f = 2000w + 64i +
// lane -> sequential 1KB stores, one contiguous run per wave (memset-like).
__global__ __launch_bounds__(256) void embed_kernel(
    const int*   __restrict__ traj_loc,   // (B,L)
    const float* __restrict__ mat2,       // (LOC,LOC)
    const float* __restrict__ vec,        // (B,L)
    const int*   __restrict__ traj_len,   // (B,)
    const float* __restrict__ emb_sl,     // (2,E)
    const float* __restrict__ emb_su,     // (2,E)
    const float* __restrict__ emb_tl,     // (2,E)
    const float* __restrict__ emb_tu,     // (2,E)
    float*       __restrict__ out)        // (B,L,LOC,E)
{
    __shared__ float srow[LOC];           // 8000 B

    const int bl = blockIdx.x;            // 0 .. B*L-1
    const int b  = bl / LL;
    const int l  = bl - b * LL;

    const bool valid = l < traj_len[b];   // block-uniform
    const int  m     = valid ? 1 : 0;

    int row = traj_loc[bl] - 1;
    row = min(max(row, 0), LOC - 1);

    const float wt = vec[bl] * (1.0f / 3600.0f);   // dt/(TU-TL)

    const int tid  = threadIdx.x;
    const int wave = tid >> 6;            // 0..3
    const int lane = tid & 63;
    const int e0   = (lane & 3) * 4;      // flat float4 index f -> e0 = (f&3)*4

    // Per-(b,l) constants: out[j,e] = base[e] + coef[e] * ds[j]
    float base[4], coef[4];
    #pragma unroll
    for (int k = 0; k < 4; ++k) {
        const int e  = e0 + k;
        const float sl = emb_sl[m * EE + e];
        const float su = emb_su[m * EE + e];
        const float tl = emb_tl[m * EE + e];
        const float tu = emb_tu[m * EE + e];
        base[k] = sl + tl * (1.0f - wt) + tu * wt;
        coef[k] = (su - sl) * (1.0f / 500.0f); // /(SU-SL)
    }

    // Block output = 8000 float4s. Wave w owns float4 indices [2000w, 2000w+2000):
    // a contiguous 32KB run, written as 31 full 1KB wave-stores + a 16-lane tail.
    float4* __restrict__ outp4 =
        reinterpret_cast<float4*>(out + (size_t)bl * LOC * EE);
    const int fbase = wave * 2000 + lane;

    if (valid) {
        // Stage mat2 row into LDS (coalesced float4, 500 total).
        const float4* __restrict__ rp4 =
            reinterpret_cast<const float4*>(mat2 + (size_t)row * LOC);
        float4* __restrict__ s4 = reinterpret_cast<float4*>(srow);
        s4[tid] = rp4[tid];
        if (tid < (LOC / 4 - 256)) s4[tid + 256] = rp4[tid + 256];
        __syncthreads();

        // srow[f>>2]: 16 consecutive addresses per wave-instruction, 4-lane
        // broadcast each -> conflict-free.
        #pragma unroll
        for (int i = 0; i < 31; ++i) {
            const int f  = fbase + i * 64;
            const float ds = srow[f >> 2];
            float4 v;
            v.x = fmaf(coef[0], ds, base[0]);
            v.y = fmaf(coef[1], ds, base[1]);
            v.z = fmaf(coef[2], ds, base[2]);
            v.w = fmaf(coef[3], ds, base[3]);
            outp4[f] = v;
        }
        if (lane < 16) {                   // tail: f = 2000w + 1984 + lane < 2000(w+1)
            const int f  = fbase + 31 * 64;
            const float ds = srow[f >> 2];
            float4 v;
            v.x = fmaf(coef[0], ds, base[0]);
            v.y = fmaf(coef[1], ds, base[1]);
            v.z = fmaf(coef[2], ds, base[2]);
            v.w = fmaf(coef[3], ds, base[3]);
            outp4[f] = v;
        }
    } else {
        // ds == 0 everywhere: constant per-lane value, pure store stream.
        float4 v;
        v.x = base[0];
        v.y = base[1];
        v.z = base[2];
        v.w = base[3];
        #pragma unroll
        for (int i = 0; i < 31; ++i) {
            outp4[fbase + i * 64] = v;
        }
        if (lane < 16) {
            outp4[fbase + 31 * 64] = v;
        }
    }
}

extern "C" void kernel_launch(void* const* d_in, const int* in_sizes, int n_in,
                              void* d_out, int out_size, void* d_ws, size_t ws_size,
                              hipStream_t stream) {
    const int*   traj_loc = (const int*)  d_in[0];
    const float* mat2     = (const float*)d_in[1];
    const float* vec      = (const float*)d_in[2];
    const int*   traj_len = (const int*)  d_in[3];
    const float* emb_sl   = (const float*)d_in[4];
    const float* emb_su   = (const float*)d_in[5];
    const float* emb_tl   = (const float*)d_in[6];
    const float* emb_tu   = (const float*)d_in[7];
    float* out = (float*)d_out;

    embed_kernel<<<BB * LL, 256, 0, stream>>>(
        traj_loc, mat2, vec, traj_len, emb_sl, emb_su, emb_tl, emb_tu, out);
}